// Round 1
// baseline (3488.033 us; speedup 1.0000x reference)
//
#include <hip/hip_runtime.h>
#include <math.h>

#define N_NODES 50000
#define N_EDGES 800000
#define BATCH   256
#define D       128
#define T       8

#define LDS_S   132   // padded stride for 128-wide LDS tiles (float4-aligned, 2-way banks max)
#define LDA_E   68    // padded stride for 64-wide LDS chunks

__device__ __forceinline__ float silu_f(float v) {
    return v / (1.0f + __expf(-v));
}

// ---------------- prep: K/V projections of cond tokens + lattice grams ----------------
__global__ __launch_bounds__(256) void prep_kernel(
    const float* __restrict__ cond,   // [B,T,D]
    const float* __restrict__ wk, const float* __restrict__ bk,
    const float* __restrict__ wv, const float* __restrict__ bv,
    const float* __restrict__ lat,    // [B,3,3]
    float* __restrict__ Kout, float* __restrict__ Vout, float* __restrict__ lip)
{
    __shared__ float condS[T * D];
    int b = blockIdx.x, tid = threadIdx.x;
    {   // 1024 floats = 256 float4
        const float4* src = (const float4*)(cond + (size_t)b * T * D);
        ((float4*)condS)[tid] = src[tid];
    }
    __syncthreads();
    #pragma unroll
    for (int i = 0; i < 8; ++i) {
        int idx = tid + i * 256;          // 0..2047
        int t = idx >> 7, d = idx & 127;
        float accK = bk[d], accV = bv[d];
        const float* c = condS + t * D;
        #pragma unroll 4
        for (int j = 0; j < D; ++j) {
            float cv = c[j];
            accK += cv * wk[j * D + d];
            accV += cv * wv[j * D + d];
        }
        Kout[(size_t)b * T * D + idx] = accK;
        Vout[(size_t)b * T * D + idx] = accV;
    }
    if (tid < 9) {
        int i = tid / 3, k = tid % 3;
        const float* Lb = lat + b * 9;
        float s = 0.f;
        #pragma unroll
        for (int j = 0; j < 3; ++j) s += Lb[i * 3 + j] * Lb[k * 3 + j];
        lip[b * 9 + tid] = s;
    }
}

// ---------------- fused cross-attention (tile of 32 nodes) ----------------
#define ATILE 32
__global__ __launch_bounds__(256) void attn_kernel(
    const float* __restrict__ h,          // node_features [N,D]
    const int*   __restrict__ node2graph,
    const float* __restrict__ frac,       // [N,3]
    const float* __restrict__ Kt, const float* __restrict__ Vt,  // [B,T,D]
    const float* __restrict__ wq, const float* __restrict__ bq,
    const float* __restrict__ wo, const float* __restrict__ bo,
    const float* __restrict__ sw1, const float* __restrict__ sb1,
    const float* __restrict__ sw2, const float* __restrict__ sb2,
    float* __restrict__ h_new)
{
    __shared__ float hs[ATILE * LDS_S];    // residual / GEMM-A
    __shared__ float buf[ATILE * LDS_S];   // tb -> Q -> ca
    __shared__ float encs[ATILE * 24];
    __shared__ float scS[ATILE * T];
    __shared__ float bS[ATILE * T];
    __shared__ int   gS[ATILE];

    int tid = threadIdx.x;
    int n0 = blockIdx.x * ATILE;
    int rows = min(ATILE, N_NODES - n0);

    // phase 0: stage h tile, graph ids, fourier enc
    #pragma unroll
    for (int i = 0; i < 4; ++i) {          // 32 rows * 32 f4 = 1024 f4
        int q = tid + i * 256;
        int m = q >> 5, c4 = q & 31;
        float4 v = make_float4(0.f, 0.f, 0.f, 0.f);
        if (m < rows) v = *(const float4*)(h + (size_t)(n0 + m) * D + c4 * 4);
        *(float4*)(hs + m * LDS_S + c4 * 4) = v;
    }
    if (tid < ATILE) gS[tid] = node2graph[min(n0 + tid, N_NODES - 1)];
    for (int idx = tid; idx < ATILE * 24; idx += 256) {
        int m = idx / 24, j = idx % 24;
        float val = 0.f;
        if (m < rows) {
            int jj = (j < 12) ? j : j - 12;
            int a = jj >> 2, f = jj & 3;
            float ph = frac[(n0 + m) * 3 + a] * ((float)(1 << f) * 3.14159265358979323846f);
            val = (j < 12) ? sinf(ph) : cosf(ph);
        }
        encs[idx] = val;
    }
    __syncthreads();

    int rowg = tid >> 4, colg = tid & 15;
    int r0 = rowg * 2, c0 = colg * 8;      // TM=2, TN=8

    // phase 1: tb = silu(encs @ sw1 + sb1) -> buf
    {
        float acc[2][8];
        #pragma unroll
        for (int i = 0; i < 2; ++i)
            #pragma unroll
            for (int j = 0; j < 8; ++j) acc[i][j] = 0.f;
        #pragma unroll 4
        for (int k = 0; k < 24; ++k) {
            float a0 = encs[(r0 + 0) * 24 + k];
            float a1 = encs[(r0 + 1) * 24 + k];
            float4 w0 = *(const float4*)(sw1 + k * D + c0);
            float4 w1 = *(const float4*)(sw1 + k * D + c0 + 4);
            float w[8] = {w0.x, w0.y, w0.z, w0.w, w1.x, w1.y, w1.z, w1.w};
            #pragma unroll
            for (int j = 0; j < 8; ++j) { acc[0][j] += a0 * w[j]; acc[1][j] += a1 * w[j]; }
        }
        #pragma unroll
        for (int i = 0; i < 2; ++i)
            #pragma unroll
            for (int j = 0; j < 8; ++j) {
                float v = acc[i][j] + sb1[c0 + j];
                buf[(r0 + i) * LDS_S + c0 + j] = silu_f(v);
            }
    }
    __syncthreads();

    // bias = tb @ sw2 + sb2
    for (int idx = tid; idx < ATILE * T; idx += 256) {
        int m = idx >> 3, t = idx & 7;
        float s = sb2[t];
        #pragma unroll 4
        for (int j = 0; j < D; ++j) s += buf[m * LDS_S + j] * sw2[j * T + t];
        bS[idx] = s;
    }
    __syncthreads();

    // phase 2: Q = hs @ wq + bq -> buf
    {
        float acc[2][8];
        #pragma unroll
        for (int i = 0; i < 2; ++i)
            #pragma unroll
            for (int j = 0; j < 8; ++j) acc[i][j] = 0.f;
        #pragma unroll 4
        for (int k = 0; k < D; ++k) {
            float a0 = hs[(r0 + 0) * LDS_S + k];
            float a1 = hs[(r0 + 1) * LDS_S + k];
            float4 w0 = *(const float4*)(wq + k * D + c0);
            float4 w1 = *(const float4*)(wq + k * D + c0 + 4);
            float w[8] = {w0.x, w0.y, w0.z, w0.w, w1.x, w1.y, w1.z, w1.w};
            #pragma unroll
            for (int j = 0; j < 8; ++j) { acc[0][j] += a0 * w[j]; acc[1][j] += a1 * w[j]; }
        }
        __syncthreads();   // everyone done reading buf (tb) via bias phase barrier above; safe to write
        #pragma unroll
        for (int i = 0; i < 2; ++i)
            #pragma unroll
            for (int j = 0; j < 8; ++j)
                buf[(r0 + i) * LDS_S + c0 + j] = acc[i][j] + bq[c0 + j];
    }
    __syncthreads();

    // phase 3: scores + softmax
    for (int idx = tid; idx < ATILE * T; idx += 256) {
        int m = idx >> 3, t = idx & 7;
        const float* Kp = Kt + ((size_t)gS[m] * T + t) * D;
        float s = 0.f;
        #pragma unroll 4
        for (int j = 0; j < D; ++j) s += buf[m * LDS_S + j] * Kp[j];
        scS[idx] = s * 0.08838834764831845f + bS[idx];   // 1/sqrt(128)
    }
    __syncthreads();
    if (tid < ATILE) {
        float mx = -1e30f;
        #pragma unroll
        for (int t = 0; t < T; ++t) mx = fmaxf(mx, scS[tid * T + t]);
        float e[T], sum = 0.f;
        #pragma unroll
        for (int t = 0; t < T; ++t) { e[t] = __expf(scS[tid * T + t] - mx); sum += e[t]; }
        float inv = 1.f / sum;
        #pragma unroll
        for (int t = 0; t < T; ++t) scS[tid * T + t] = e[t] * inv;
    }
    __syncthreads();

    // phase 4: ca = attn @ V  -> buf (Q dead)
    #pragma unroll
    for (int i = 0; i < 16; ++i) {         // 4096 outputs / 256
        int idx = tid + i * 256;
        int m = idx >> 7, c = idx & 127;
        const float* Vp = Vt + (size_t)gS[m] * T * D + c;
        float s = 0.f;
        #pragma unroll
        for (int t = 0; t < T; ++t) s += scS[m * T + t] * Vp[t * D];
        buf[m * LDS_S + c] = s;
    }
    __syncthreads();

    // phase 5: h_new = hs + buf @ wo + bo
    {
        float acc[2][8];
        #pragma unroll
        for (int i = 0; i < 2; ++i)
            #pragma unroll
            for (int j = 0; j < 8; ++j) acc[i][j] = 0.f;
        #pragma unroll 4
        for (int k = 0; k < D; ++k) {
            float a0 = buf[(r0 + 0) * LDS_S + k];
            float a1 = buf[(r0 + 1) * LDS_S + k];
            float4 w0 = *(const float4*)(wo + k * D + c0);
            float4 w1 = *(const float4*)(wo + k * D + c0 + 4);
            float w[8] = {w0.x, w0.y, w0.z, w0.w, w1.x, w1.y, w1.z, w1.w};
            #pragma unroll
            for (int j = 0; j < 8; ++j) { acc[0][j] += a0 * w[j]; acc[1][j] += a1 * w[j]; }
        }
        #pragma unroll
        for (int i = 0; i < 2; ++i) {
            int m = r0 + i;
            if (m < rows) {
                #pragma unroll
                for (int j = 0; j < 8; ++j) {
                    float v = acc[i][j] + bo[c0 + j] + hs[m * LDS_S + c0 + j];
                    h_new[(size_t)(n0 + m) * D + c0 + j] = v;
                }
            }
        }
    }
}

// ---------------- fused edge MLP + scatter (tile of 64 edges) ----------------
__global__ __launch_bounds__(256) void edge_kernel(
    const float* __restrict__ h_new,
    const float* __restrict__ frac,
    const int*   __restrict__ edges,   // [2,E]
    const int*   __restrict__ e2g,
    const float* __restrict__ lip,     // [B,9]
    const float* __restrict__ ew1, const float* __restrict__ eb1,
    const float* __restrict__ ew2, const float* __restrict__ eb2,
    float* __restrict__ agg, float* __restrict__ cnt)
{
    __shared__ float As[64 * LDA_E];
    __shared__ float t1[64 * LDS_S];
    __shared__ float tailS[64 * 12];
    __shared__ int e0S[64], e1S[64];

    int tid = threadIdx.x;
    int m0 = blockIdx.x * 64;
    if (tid < 64) {
        e0S[tid] = edges[m0 + tid];
        e1S[tid] = edges[N_EDGES + m0 + tid];
    }
    __syncthreads();
    // tail features: lip (9) + fd (3)
    for (int idx = tid; idx < 64 * 12; idx += 256) {
        int m = idx / 12, j = idx % 12;
        float v;
        if (j < 9) v = lip[e2g[m0 + m] * 9 + j];
        else {
            int a = j - 9;
            float d = frac[e1S[m] * 3 + a] - frac[e0S[m] * 3 + a];
            v = d - floorf(d);
        }
        tailS[m * 12 + j] = v;
    }

    int rowg = tid >> 4, colg = tid & 15;
    int r0 = rowg * 4, c0 = colg * 8;
    float acc[4][8];
    #pragma unroll
    for (int i = 0; i < 4; ++i)
        #pragma unroll
        for (int j = 0; j < 8; ++j) acc[i][j] = 0.f;

    // 4 chunks of 64 k's from gathered h rows
    for (int ch = 0; ch < 4; ++ch) {
        const int* srci = (ch < 2) ? e0S : e1S;
        int base = (ch & 1) * 64;
        __syncthreads();
        #pragma unroll
        for (int i = 0; i < 4; ++i) {      // 64 rows * 16 f4
            int q = tid + i * 256;
            int m = q >> 4, c4 = q & 15;
            *(float4*)(As + m * LDA_E + c4 * 4) =
                *(const float4*)(h_new + (size_t)srci[m] * D + base + c4 * 4);
        }
        __syncthreads();
        int kb = ch * 64;
        #pragma unroll 4
        for (int k = 0; k < 64; ++k) {
            float a0 = As[(r0 + 0) * LDA_E + k];
            float a1 = As[(r0 + 1) * LDA_E + k];
            float a2 = As[(r0 + 2) * LDA_E + k];
            float a3 = As[(r0 + 3) * LDA_E + k];
            float4 w0 = *(const float4*)(ew1 + (kb + k) * D + c0);
            float4 w1 = *(const float4*)(ew1 + (kb + k) * D + c0 + 4);
            float w[8] = {w0.x, w0.y, w0.z, w0.w, w1.x, w1.y, w1.z, w1.w};
            #pragma unroll
            for (int j = 0; j < 8; ++j) {
                acc[0][j] += a0 * w[j]; acc[1][j] += a1 * w[j];
                acc[2][j] += a2 * w[j]; acc[3][j] += a3 * w[j];
            }
        }
    }
    // tail 12 k's
    #pragma unroll
    for (int k = 0; k < 12; ++k) {
        float a0 = tailS[(r0 + 0) * 12 + k];
        float a1 = tailS[(r0 + 1) * 12 + k];
        float a2 = tailS[(r0 + 2) * 12 + k];
        float a3 = tailS[(r0 + 3) * 12 + k];
        float4 w0 = *(const float4*)(ew1 + (256 + k) * D + c0);
        float4 w1 = *(const float4*)(ew1 + (256 + k) * D + c0 + 4);
        float w[8] = {w0.x, w0.y, w0.z, w0.w, w1.x, w1.y, w1.z, w1.w};
        #pragma unroll
        for (int j = 0; j < 8; ++j) {
            acc[0][j] += a0 * w[j]; acc[1][j] += a1 * w[j];
            acc[2][j] += a2 * w[j]; acc[3][j] += a3 * w[j];
        }
    }
    // silu -> t1
    #pragma unroll
    for (int i = 0; i < 4; ++i)
        #pragma unroll
        for (int j = 0; j < 8; ++j)
            t1[(r0 + i) * LDS_S + c0 + j] = silu_f(acc[i][j] + eb1[c0 + j]);
    __syncthreads();

    // GEMM2: silu(t1 @ ew2 + eb2)
    float acc2[4][8];
    #pragma unroll
    for (int i = 0; i < 4; ++i)
        #pragma unroll
        for (int j = 0; j < 8; ++j) acc2[i][j] = 0.f;
    #pragma unroll 4
    for (int k = 0; k < D; ++k) {
        float a0 = t1[(r0 + 0) * LDS_S + k];
        float a1 = t1[(r0 + 1) * LDS_S + k];
        float a2 = t1[(r0 + 2) * LDS_S + k];
        float a3 = t1[(r0 + 3) * LDS_S + k];
        float4 w0 = *(const float4*)(ew2 + k * D + c0);
        float4 w1 = *(const float4*)(ew2 + k * D + c0 + 4);
        float w[8] = {w0.x, w0.y, w0.z, w0.w, w1.x, w1.y, w1.z, w1.w};
        #pragma unroll
        for (int j = 0; j < 8; ++j) {
            acc2[0][j] += a0 * w[j]; acc2[1][j] += a1 * w[j];
            acc2[2][j] += a2 * w[j]; acc2[3][j] += a3 * w[j];
        }
    }
    // scatter
    #pragma unroll
    for (int i = 0; i < 4; ++i) {
        int e0 = e0S[r0 + i];
        #pragma unroll
        for (int j = 0; j < 8; ++j) {
            float v = silu_f(acc2[i][j] + eb2[c0 + j]);
            atomicAdd(&agg[(size_t)e0 * D + c0 + j], v);
        }
    }
    if (colg == 0) {
        #pragma unroll
        for (int i = 0; i < 4; ++i) atomicAdd(&cnt[e0S[r0 + i]], 1.0f);
    }
}

// ---------------- fused node MLP + residual (tile of 64 nodes) ----------------
__global__ __launch_bounds__(256) void node_kernel(
    const float* __restrict__ node_features,
    const float* __restrict__ h_new,
    const float* __restrict__ agg, const float* __restrict__ cnt,
    const float* __restrict__ nw1, const float* __restrict__ nb1,
    const float* __restrict__ nw2, const float* __restrict__ nb2,
    float* __restrict__ out)
{
    __shared__ float As[64 * LDA_E];
    __shared__ float t1[64 * LDS_S];
    int tid = threadIdx.x;
    int n0 = blockIdx.x * 64;
    int rows = min(64, N_NODES - n0);
    int rowg = tid >> 4, colg = tid & 15;
    int r0 = rowg * 4, c0 = colg * 8;
    float acc[4][8];
    #pragma unroll
    for (int i = 0; i < 4; ++i)
        #pragma unroll
        for (int j = 0; j < 8; ++j) acc[i][j] = 0.f;

    for (int ch = 0; ch < 4; ++ch) {
        __syncthreads();
        #pragma unroll
        for (int i = 0; i < 4; ++i) {
            int q = tid + i * 256;
            int m = q >> 4, c4 = q & 15;
            float4 v = make_float4(0.f, 0.f, 0.f, 0.f);
            if (m < rows) {
                int col = (ch & 1) * 64 + c4 * 4;
                if (ch < 2) {
                    v = *(const float4*)(h_new + (size_t)(n0 + m) * D + col);
                } else {
                    float4 a = *(const float4*)(agg + (size_t)(n0 + m) * D + col);
                    float inv = 1.0f / fmaxf(cnt[n0 + m], 1.0f);
                    v = make_float4(a.x * inv, a.y * inv, a.z * inv, a.w * inv);
                }
            }
            *(float4*)(As + m * LDA_E + c4 * 4) = v;
        }
        __syncthreads();
        int kb = ch * 64;
        #pragma unroll 4
        for (int k = 0; k < 64; ++k) {
            float a0 = As[(r0 + 0) * LDA_E + k];
            float a1 = As[(r0 + 1) * LDA_E + k];
            float a2 = As[(r0 + 2) * LDA_E + k];
            float a3 = As[(r0 + 3) * LDA_E + k];
            float4 w0 = *(const float4*)(nw1 + (kb + k) * D + c0);
            float4 w1 = *(const float4*)(nw1 + (kb + k) * D + c0 + 4);
            float w[8] = {w0.x, w0.y, w0.z, w0.w, w1.x, w1.y, w1.z, w1.w};
            #pragma unroll
            for (int j = 0; j < 8; ++j) {
                acc[0][j] += a0 * w[j]; acc[1][j] += a1 * w[j];
                acc[2][j] += a2 * w[j]; acc[3][j] += a3 * w[j];
            }
        }
    }
    #pragma unroll
    for (int i = 0; i < 4; ++i)
        #pragma unroll
        for (int j = 0; j < 8; ++j)
            t1[(r0 + i) * LDS_S + c0 + j] = silu_f(acc[i][j] + nb1[c0 + j]);
    __syncthreads();

    float acc2[4][8];
    #pragma unroll
    for (int i = 0; i < 4; ++i)
        #pragma unroll
        for (int j = 0; j < 8; ++j) acc2[i][j] = 0.f;
    #pragma unroll 4
    for (int k = 0; k < D; ++k) {
        float a0 = t1[(r0 + 0) * LDS_S + k];
        float a1 = t1[(r0 + 1) * LDS_S + k];
        float a2 = t1[(r0 + 2) * LDS_S + k];
        float a3 = t1[(r0 + 3) * LDS_S + k];
        float4 w0 = *(const float4*)(nw2 + k * D + c0);
        float4 w1 = *(const float4*)(nw2 + k * D + c0 + 4);
        float w[8] = {w0.x, w0.y, w0.z, w0.w, w1.x, w1.y, w1.z, w1.w};
        #pragma unroll
        for (int j = 0; j < 8; ++j) {
            acc2[0][j] += a0 * w[j]; acc2[1][j] += a1 * w[j];
            acc2[2][j] += a2 * w[j]; acc2[3][j] += a3 * w[j];
        }
    }
    #pragma unroll
    for (int i = 0; i < 4; ++i) {
        int m = r0 + i;
        if (m < rows) {
            #pragma unroll
            for (int j = 0; j < 8; ++j) {
                float v = silu_f(acc2[i][j] + nb2[c0 + j]);
                out[(size_t)(n0 + m) * D + c0 + j] =
                    node_features[(size_t)(n0 + m) * D + c0 + j] + v;
            }
        }
    }
}

extern "C" void kernel_launch(void* const* d_in, const int* in_sizes, int n_in,
                              void* d_out, int out_size, void* d_ws, size_t ws_size,
                              hipStream_t stream) {
    const float* node_features = (const float*)d_in[0];
    const float* cond          = (const float*)d_in[1];
    const int*   node2graph    = (const int*)d_in[2];
    const float* frac          = (const float*)d_in[3];
    const float* lat           = (const float*)d_in[4];
    const int*   edges         = (const int*)d_in[5];
    const int*   e2g           = (const int*)d_in[6];
    const float* wq = (const float*)d_in[7];  const float* bq = (const float*)d_in[8];
    const float* wk = (const float*)d_in[9];  const float* bk = (const float*)d_in[10];
    const float* wv = (const float*)d_in[11]; const float* bv = (const float*)d_in[12];
    const float* wo = (const float*)d_in[13]; const float* bo = (const float*)d_in[14];
    const float* sw1 = (const float*)d_in[15]; const float* sb1 = (const float*)d_in[16];
    const float* sw2 = (const float*)d_in[17]; const float* sb2 = (const float*)d_in[18];
    const float* ew1 = (const float*)d_in[19]; const float* eb1 = (const float*)d_in[20];
    const float* ew2 = (const float*)d_in[21]; const float* eb2 = (const float*)d_in[22];
    const float* nw1 = (const float*)d_in[23]; const float* nb1 = (const float*)d_in[24];
    const float* nw2 = (const float*)d_in[25]; const float* nb2 = (const float*)d_in[26];
    float* out = (float*)d_out;

    float* ws    = (float*)d_ws;
    float* h_new = ws;                                   // N*D
    float* agg   = h_new + (size_t)N_NODES * D;          // N*D
    float* cnt   = agg + (size_t)N_NODES * D;            // N
    float* Kt    = cnt + N_NODES;                        // B*T*D
    float* Vt    = Kt + (size_t)BATCH * T * D;           // B*T*D
    float* lip   = Vt + (size_t)BATCH * T * D;           // B*9

    hipMemsetAsync(agg, 0, ((size_t)N_NODES * D + N_NODES) * sizeof(float), stream);
    prep_kernel<<<BATCH, 256, 0, stream>>>(cond, wk, bk, wv, bv, lat, Kt, Vt, lip);
    attn_kernel<<<(N_NODES + ATILE - 1) / ATILE, 256, 0, stream>>>(
        node_features, node2graph, frac, Kt, Vt, wq, bq, wo, bo, sw1, sb1, sw2, sb2, h_new);
    edge_kernel<<<N_EDGES / 64, 256, 0, stream>>>(
        h_new, frac, edges, e2g, lip, ew1, eb1, ew2, eb2, agg, cnt);
    node_kernel<<<(N_NODES + 63) / 64, 256, 0, stream>>>(
        node_features, h_new, agg, cnt, nw1, nb1, nw2, nb2, out);
}

// Round 3
// 1747.838 us; speedup vs baseline: 1.9956x; 1.9956x over previous
//
#include <hip/hip_runtime.h>
#include <math.h>

#define N_NODES 50000
#define N_EDGES 800000
#define BATCH   256
#define D       128
#define T       8

#define LDS_S   132   // padded stride for 128-wide LDS tiles in attn kernel
#define LDA_E   68    // padded stride for 64-wide LDS chunks

__device__ __forceinline__ float silu_f(float v) {
    return v / (1.0f + __expf(-v));
}

// ---------------- prep: K/V projections of cond tokens + lattice grams ----------------
__global__ __launch_bounds__(256) void prep_kernel(
    const float* __restrict__ cond,   // [B,T,D]
    const float* __restrict__ wk, const float* __restrict__ bk,
    const float* __restrict__ wv, const float* __restrict__ bv,
    const float* __restrict__ lat,    // [B,3,3]
    float* __restrict__ Kout, float* __restrict__ Vout, float* __restrict__ lip)
{
    __shared__ float condS[T * D];
    int b = blockIdx.x, tid = threadIdx.x;
    {   // 1024 floats = 256 float4
        const float4* src = (const float4*)(cond + (size_t)b * T * D);
        ((float4*)condS)[tid] = src[tid];
    }
    __syncthreads();
    #pragma unroll
    for (int i = 0; i < 8; ++i) {
        int idx = tid + i * 256;          // 0..2047
        int t = idx >> 7, d = idx & 127;
        float accK = bk[d], accV = bv[d];
        const float* c = condS + t * D;
        #pragma unroll 4
        for (int j = 0; j < D; ++j) {
            float cv = c[j];
            accK += cv * wk[j * D + d];
            accV += cv * wv[j * D + d];
        }
        Kout[(size_t)b * T * D + idx] = accK;
        Vout[(size_t)b * T * D + idx] = accV;
    }
    if (tid < 9) {
        int i = tid / 3, k = tid % 3;
        const float* Lb = lat + b * 9;
        float s = 0.f;
        #pragma unroll
        for (int j = 0; j < 3; ++j) s += Lb[i * 3 + j] * Lb[k * 3 + j];
        lip[b * 9 + tid] = s;
    }
}

// ---------------- fused cross-attention (tile of 32 nodes) ----------------
#define ATILE 32
__global__ __launch_bounds__(256) void attn_kernel(
    const float* __restrict__ h,          // node_features [N,D]
    const int*   __restrict__ node2graph,
    const float* __restrict__ frac,       // [N,3]
    const float* __restrict__ Kt, const float* __restrict__ Vt,  // [B,T,D]
    const float* __restrict__ wq, const float* __restrict__ bq,
    const float* __restrict__ wo, const float* __restrict__ bo,
    const float* __restrict__ sw1, const float* __restrict__ sb1,
    const float* __restrict__ sw2, const float* __restrict__ sb2,
    float* __restrict__ h_new)
{
    __shared__ float hs[ATILE * LDS_S];    // residual / GEMM-A
    __shared__ float buf[ATILE * LDS_S];   // tb -> Q -> ca
    __shared__ float encs[ATILE * 24];
    __shared__ float scS[ATILE * T];
    __shared__ float bS[ATILE * T];
    __shared__ int   gS[ATILE];

    int tid = threadIdx.x;
    int n0 = blockIdx.x * ATILE;
    int rows = min(ATILE, N_NODES - n0);

    // phase 0: stage h tile, graph ids, fourier enc
    #pragma unroll
    for (int i = 0; i < 4; ++i) {          // 32 rows * 32 f4 = 1024 f4
        int q = tid + i * 256;
        int m = q >> 5, c4 = q & 31;
        float4 v = make_float4(0.f, 0.f, 0.f, 0.f);
        if (m < rows) v = *(const float4*)(h + (size_t)(n0 + m) * D + c4 * 4);
        *(float4*)(hs + m * LDS_S + c4 * 4) = v;
    }
    if (tid < ATILE) gS[tid] = node2graph[min(n0 + tid, N_NODES - 1)];
    for (int idx = tid; idx < ATILE * 24; idx += 256) {
        int m = idx / 24, j = idx % 24;
        float val = 0.f;
        if (m < rows) {
            int jj = (j < 12) ? j : j - 12;
            int a = jj >> 2, f = jj & 3;
            float ph = frac[(n0 + m) * 3 + a] * ((float)(1 << f) * 3.14159265358979323846f);
            val = (j < 12) ? sinf(ph) : cosf(ph);
        }
        encs[idx] = val;
    }
    __syncthreads();

    int rowg = tid >> 4, colg = tid & 15;
    int r0 = rowg * 2, c0 = colg * 8;      // TM=2, TN=8

    // phase 1: tb = silu(encs @ sw1 + sb1) -> buf
    {
        float acc[2][8];
        #pragma unroll
        for (int i = 0; i < 2; ++i)
            #pragma unroll
            for (int j = 0; j < 8; ++j) acc[i][j] = 0.f;
        #pragma unroll 4
        for (int k = 0; k < 24; ++k) {
            float a0 = encs[(r0 + 0) * 24 + k];
            float a1 = encs[(r0 + 1) * 24 + k];
            float4 w0 = *(const float4*)(sw1 + k * D + c0);
            float4 w1 = *(const float4*)(sw1 + k * D + c0 + 4);
            float w[8] = {w0.x, w0.y, w0.z, w0.w, w1.x, w1.y, w1.z, w1.w};
            #pragma unroll
            for (int j = 0; j < 8; ++j) { acc[0][j] += a0 * w[j]; acc[1][j] += a1 * w[j]; }
        }
        #pragma unroll
        for (int i = 0; i < 2; ++i)
            #pragma unroll
            for (int j = 0; j < 8; ++j) {
                float v = acc[i][j] + sb1[c0 + j];
                buf[(r0 + i) * LDS_S + c0 + j] = silu_f(v);
            }
    }
    __syncthreads();

    // bias = tb @ sw2 + sb2
    for (int idx = tid; idx < ATILE * T; idx += 256) {
        int m = idx >> 3, t = idx & 7;
        float s = sb2[t];
        #pragma unroll 4
        for (int j = 0; j < D; ++j) s += buf[m * LDS_S + j] * sw2[j * T + t];
        bS[idx] = s;
    }
    __syncthreads();

    // phase 2: Q = hs @ wq + bq -> buf
    {
        float acc[2][8];
        #pragma unroll
        for (int i = 0; i < 2; ++i)
            #pragma unroll
            for (int j = 0; j < 8; ++j) acc[i][j] = 0.f;
        #pragma unroll 4
        for (int k = 0; k < D; ++k) {
            float a0 = hs[(r0 + 0) * LDS_S + k];
            float a1 = hs[(r0 + 1) * LDS_S + k];
            float4 w0 = *(const float4*)(wq + k * D + c0);
            float4 w1 = *(const float4*)(wq + k * D + c0 + 4);
            float w[8] = {w0.x, w0.y, w0.z, w0.w, w1.x, w1.y, w1.z, w1.w};
            #pragma unroll
            for (int j = 0; j < 8; ++j) { acc[0][j] += a0 * w[j]; acc[1][j] += a1 * w[j]; }
        }
        __syncthreads();
        #pragma unroll
        for (int i = 0; i < 2; ++i)
            #pragma unroll
            for (int j = 0; j < 8; ++j)
                buf[(r0 + i) * LDS_S + c0 + j] = acc[i][j] + bq[c0 + j];
    }
    __syncthreads();

    // phase 3: scores + softmax
    for (int idx = tid; idx < ATILE * T; idx += 256) {
        int m = idx >> 3, t = idx & 7;
        const float* Kp = Kt + ((size_t)gS[m] * T + t) * D;
        float s = 0.f;
        #pragma unroll 4
        for (int j = 0; j < D; ++j) s += buf[m * LDS_S + j] * Kp[j];
        scS[idx] = s * 0.08838834764831845f + bS[idx];   // 1/sqrt(128)
    }
    __syncthreads();
    if (tid < ATILE) {
        float mx = -1e30f;
        #pragma unroll
        for (int t = 0; t < T; ++t) mx = fmaxf(mx, scS[tid * T + t]);
        float e[T], sum = 0.f;
        #pragma unroll
        for (int t = 0; t < T; ++t) { e[t] = __expf(scS[tid * T + t] - mx); sum += e[t]; }
        float inv = 1.f / sum;
        #pragma unroll
        for (int t = 0; t < T; ++t) scS[tid * T + t] = e[t] * inv;
    }
    __syncthreads();

    // phase 4: ca = attn @ V  -> buf (Q dead)
    #pragma unroll
    for (int i = 0; i < 16; ++i) {         // 4096 outputs / 256
        int idx = tid + i * 256;
        int m = idx >> 7, c = idx & 127;
        const float* Vp = Vt + (size_t)gS[m] * T * D + c;
        float s = 0.f;
        #pragma unroll
        for (int t = 0; t < T; ++t) s += scS[m * T + t] * Vp[t * D];
        buf[m * LDS_S + c] = s;
    }
    __syncthreads();

    // phase 5: h_new = hs + buf @ wo + bo
    {
        float acc[2][8];
        #pragma unroll
        for (int i = 0; i < 2; ++i)
            #pragma unroll
            for (int j = 0; j < 8; ++j) acc[i][j] = 0.f;
        #pragma unroll 4
        for (int k = 0; k < D; ++k) {
            float a0 = buf[(r0 + 0) * LDS_S + k];
            float a1 = buf[(r0 + 1) * LDS_S + k];
            float4 w0 = *(const float4*)(wo + k * D + c0);
            float4 w1 = *(const float4*)(wo + k * D + c0 + 4);
            float w[8] = {w0.x, w0.y, w0.z, w0.w, w1.x, w1.y, w1.z, w1.w};
            #pragma unroll
            for (int j = 0; j < 8; ++j) { acc[0][j] += a0 * w[j]; acc[1][j] += a1 * w[j]; }
        }
        #pragma unroll
        for (int i = 0; i < 2; ++i) {
            int m = r0 + i;
            if (m < rows) {
                #pragma unroll
                for (int j = 0; j < 8; ++j) {
                    float v = acc[i][j] + bo[c0 + j] + hs[m * LDS_S + c0 + j];
                    h_new[(size_t)(n0 + m) * D + c0 + j] = v;
                }
            }
        }
    }
}

// ---------------- fused edge MLP + coalesced scatter (tile of 64 edges) ----------------
// LDS: t1[64*128] (32KB) doubles as As[64*LDA_E] (17.4KB, aliased) and as the
// scatter staging buffer. Total ~36.4KB -> 4 blocks/CU (16 waves) vs 2 before.
__global__ __launch_bounds__(256) void edge_kernel(
    const float* __restrict__ h_new,
    const float* __restrict__ frac,
    const int*   __restrict__ edges,   // [2,E]
    const int*   __restrict__ e2g,
    const float* __restrict__ lip,     // [B,9]
    const float* __restrict__ ew1, const float* __restrict__ eb1,
    const float* __restrict__ ew2, const float* __restrict__ eb2,
    float* __restrict__ agg, float* __restrict__ cnt)
{
    __shared__ float t1[64 * 128];
    __shared__ float tailS[64 * 12];
    __shared__ int e0S[64], e1S[64];
    float* As = t1;   // aliased: As live only during chunk loop, t1 only after

    int tid = threadIdx.x;
    int m0 = blockIdx.x * 64;
    if (tid < 64) {
        e0S[tid] = edges[m0 + tid];
        e1S[tid] = edges[N_EDGES + m0 + tid];
    }
    __syncthreads();
    // tail features: lip (9) + fd (3)
    for (int idx = tid; idx < 64 * 12; idx += 256) {
        int m = idx / 12, j = idx % 12;
        float v;
        if (j < 9) v = lip[e2g[m0 + m] * 9 + j];
        else {
            int a = j - 9;
            float d = frac[e1S[m] * 3 + a] - frac[e0S[m] * 3 + a];
            v = d - floorf(d);
        }
        tailS[m * 12 + j] = v;
    }

    int rowg = tid >> 4, colg = tid & 15;
    int r0 = rowg * 4, c0 = colg * 8;
    float acc[4][8];
    #pragma unroll
    for (int i = 0; i < 4; ++i)
        #pragma unroll
        for (int j = 0; j < 8; ++j) acc[i][j] = 0.f;

    // 4 chunks of 64 k's from gathered h rows
    for (int ch = 0; ch < 4; ++ch) {
        const int* srci = (ch < 2) ? e0S : e1S;
        int base = (ch & 1) * 64;
        __syncthreads();
        #pragma unroll
        for (int i = 0; i < 4; ++i) {      // 64 rows * 16 f4
            int q = tid + i * 256;
            int m = q >> 4, c4 = q & 15;
            *(float4*)(As + m * LDA_E + c4 * 4) =
                *(const float4*)(h_new + (size_t)srci[m] * D + base + c4 * 4);
        }
        __syncthreads();
        int kb = ch * 64;
        #pragma unroll 4
        for (int k = 0; k < 64; ++k) {
            float a0 = As[(r0 + 0) * LDA_E + k];
            float a1 = As[(r0 + 1) * LDA_E + k];
            float a2 = As[(r0 + 2) * LDA_E + k];
            float a3 = As[(r0 + 3) * LDA_E + k];
            float4 w0 = *(const float4*)(ew1 + (kb + k) * D + c0);
            float4 w1 = *(const float4*)(ew1 + (kb + k) * D + c0 + 4);
            float w[8] = {w0.x, w0.y, w0.z, w0.w, w1.x, w1.y, w1.z, w1.w};
            #pragma unroll
            for (int j = 0; j < 8; ++j) {
                acc[0][j] += a0 * w[j]; acc[1][j] += a1 * w[j];
                acc[2][j] += a2 * w[j]; acc[3][j] += a3 * w[j];
            }
        }
    }
    // tail 12 k's
    #pragma unroll
    for (int k = 0; k < 12; ++k) {
        float a0 = tailS[(r0 + 0) * 12 + k];
        float a1 = tailS[(r0 + 1) * 12 + k];
        float a2 = tailS[(r0 + 2) * 12 + k];
        float a3 = tailS[(r0 + 3) * 12 + k];
        float4 w0 = *(const float4*)(ew1 + (256 + k) * D + c0);
        float4 w1 = *(const float4*)(ew1 + (256 + k) * D + c0 + 4);
        float w[8] = {w0.x, w0.y, w0.z, w0.w, w1.x, w1.y, w1.z, w1.w};
        #pragma unroll
        for (int j = 0; j < 8; ++j) {
            acc[0][j] += a0 * w[j]; acc[1][j] += a1 * w[j];
            acc[2][j] += a2 * w[j]; acc[3][j] += a3 * w[j];
        }
    }
    __syncthreads();   // everyone done reading As before t1 (aliased) is written
    // silu -> t1 (stride 128; GEMM2 reads are wave-broadcast, no conflicts)
    #pragma unroll
    for (int i = 0; i < 4; ++i)
        #pragma unroll
        for (int j = 0; j < 8; ++j)
            t1[(r0 + i) * 128 + c0 + j] = silu_f(acc[i][j] + eb1[c0 + j]);
    __syncthreads();

    // GEMM2: silu(t1 @ ew2 + eb2)
    float acc2[4][8];
    #pragma unroll
    for (int i = 0; i < 4; ++i)
        #pragma unroll
        for (int j = 0; j < 8; ++j) acc2[i][j] = 0.f;
    #pragma unroll 4
    for (int k = 0; k < D; ++k) {
        float a0 = t1[(r0 + 0) * 128 + k];
        float a1 = t1[(r0 + 1) * 128 + k];
        float a2 = t1[(r0 + 2) * 128 + k];
        float a3 = t1[(r0 + 3) * 128 + k];
        float4 w0 = *(const float4*)(ew2 + k * D + c0);
        float4 w1 = *(const float4*)(ew2 + k * D + c0 + 4);
        float w[8] = {w0.x, w0.y, w0.z, w0.w, w1.x, w1.y, w1.z, w1.w};
        #pragma unroll
        for (int j = 0; j < 8; ++j) {
            acc2[0][j] += a0 * w[j]; acc2[1][j] += a1 * w[j];
            acc2[2][j] += a2 * w[j]; acc2[3][j] += a3 * w[j];
        }
    }
    __syncthreads();   // everyone done reading t1; reuse as scatter staging
    #pragma unroll
    for (int i = 0; i < 4; ++i)
        #pragma unroll
        for (int j = 0; j < 8; ++j)
            t1[(r0 + i) * 128 + c0 + j] = silu_f(acc2[i][j] + eb2[c0 + j]);
    __syncthreads();

    // coalesced scatter: each wave -> 64 consecutive dwords of one edge row
    // (256B contiguous per wave-instruction; sectors fully covered)
    int srow = tid >> 7, scol = tid & 127;
    #pragma unroll
    for (int p = 0; p < 32; ++p) {
        int row = p * 2 + srow;
        atomicAdd(&agg[(size_t)e0S[row] * D + scol], t1[row * 128 + scol]);
    }
    if (tid < 64) atomicAdd(&cnt[e0S[tid]], 1.0f);
}

// ---------------- fused node MLP + residual (tile of 64 nodes) ----------------
__global__ __launch_bounds__(256) void node_kernel(
    const float* __restrict__ node_features,
    const float* __restrict__ h_new,
    const float* __restrict__ agg, const float* __restrict__ cnt,
    const float* __restrict__ nw1, const float* __restrict__ nb1,
    const float* __restrict__ nw2, const float* __restrict__ nb2,
    float* __restrict__ out)
{
    __shared__ float t1[64 * 128];
    float* As = t1;   // aliased as in edge_kernel
    int tid = threadIdx.x;
    int n0 = blockIdx.x * 64;
    int rows = min(64, N_NODES - n0);
    int rowg = tid >> 4, colg = tid & 15;
    int r0 = rowg * 4, c0 = colg * 8;
    float acc[4][8];
    #pragma unroll
    for (int i = 0; i < 4; ++i)
        #pragma unroll
        for (int j = 0; j < 8; ++j) acc[i][j] = 0.f;

    for (int ch = 0; ch < 4; ++ch) {
        __syncthreads();
        #pragma unroll
        for (int i = 0; i < 4; ++i) {
            int q = tid + i * 256;
            int m = q >> 4, c4 = q & 15;
            float4 v = make_float4(0.f, 0.f, 0.f, 0.f);
            if (m < rows) {
                int col = (ch & 1) * 64 + c4 * 4;
                if (ch < 2) {
                    v = *(const float4*)(h_new + (size_t)(n0 + m) * D + col);
                } else {
                    float4 a = *(const float4*)(agg + (size_t)(n0 + m) * D + col);
                    float inv = 1.0f / fmaxf(cnt[n0 + m], 1.0f);
                    v = make_float4(a.x * inv, a.y * inv, a.z * inv, a.w * inv);
                }
            }
            *(float4*)(As + m * LDA_E + c4 * 4) = v;
        }
        __syncthreads();
        int kb = ch * 64;
        #pragma unroll 4
        for (int k = 0; k < 64; ++k) {
            float a0 = As[(r0 + 0) * LDA_E + k];
            float a1 = As[(r0 + 1) * LDA_E + k];
            float a2 = As[(r0 + 2) * LDA_E + k];
            float a3 = As[(r0 + 3) * LDA_E + k];
            float4 w0 = *(const float4*)(nw1 + (kb + k) * D + c0);
            float4 w1 = *(const float4*)(nw1 + (kb + k) * D + c0 + 4);
            float w[8] = {w0.x, w0.y, w0.z, w0.w, w1.x, w1.y, w1.z, w1.w};
            #pragma unroll
            for (int j = 0; j < 8; ++j) {
                acc[0][j] += a0 * w[j]; acc[1][j] += a1 * w[j];
                acc[2][j] += a2 * w[j]; acc[3][j] += a3 * w[j];
            }
        }
    }
    __syncthreads();   // done reading As before aliased t1 write
    #pragma unroll
    for (int i = 0; i < 4; ++i)
        #pragma unroll
        for (int j = 0; j < 8; ++j)
            t1[(r0 + i) * 128 + c0 + j] = silu_f(acc[i][j] + nb1[c0 + j]);
    __syncthreads();

    float acc2[4][8];
    #pragma unroll
    for (int i = 0; i < 4; ++i)
        #pragma unroll
        for (int j = 0; j < 8; ++j) acc2[i][j] = 0.f;
    #pragma unroll 4
    for (int k = 0; k < D; ++k) {
        float a0 = t1[(r0 + 0) * 128 + k];
        float a1 = t1[(r0 + 1) * 128 + k];
        float a2 = t1[(r0 + 2) * 128 + k];
        float a3 = t1[(r0 + 3) * 128 + k];
        float4 w0 = *(const float4*)(nw2 + k * D + c0);
        float4 w1 = *(const float4*)(nw2 + k * D + c0 + 4);
        float w[8] = {w0.x, w0.y, w0.z, w0.w, w1.x, w1.y, w1.z, w1.w};
        #pragma unroll
        for (int j = 0; j < 8; ++j) {
            acc2[0][j] += a0 * w[j]; acc2[1][j] += a1 * w[j];
            acc2[2][j] += a2 * w[j]; acc2[3][j] += a3 * w[j];
        }
    }
    #pragma unroll
    for (int i = 0; i < 4; ++i) {
        int m = r0 + i;
        if (m < rows) {
            #pragma unroll
            for (int j = 0; j < 8; ++j) {
                float v = silu_f(acc2[i][j] + nb2[c0 + j]);
                out[(size_t)(n0 + m) * D + c0 + j] =
                    node_features[(size_t)(n0 + m) * D + c0 + j] + v;
            }
        }
    }
}

extern "C" void kernel_launch(void* const* d_in, const int* in_sizes, int n_in,
                              void* d_out, int out_size, void* d_ws, size_t ws_size,
                              hipStream_t stream) {
    const float* node_features = (const float*)d_in[0];
    const float* cond          = (const float*)d_in[1];
    const int*   node2graph    = (const int*)d_in[2];
    const float* frac          = (const float*)d_in[3];
    const float* lat           = (const float*)d_in[4];
    const int*   edges         = (const int*)d_in[5];
    const int*   e2g           = (const int*)d_in[6];
    const float* wq = (const float*)d_in[7];  const float* bq = (const float*)d_in[8];
    const float* wk = (const float*)d_in[9];  const float* bk = (const float*)d_in[10];
    const float* wv = (const float*)d_in[11]; const float* bv = (const float*)d_in[12];
    const float* wo = (const float*)d_in[13]; const float* bo = (const float*)d_in[14];
    const float* sw1 = (const float*)d_in[15]; const float* sb1 = (const float*)d_in[16];
    const float* sw2 = (const float*)d_in[17]; const float* sb2 = (const float*)d_in[18];
    const float* ew1 = (const float*)d_in[19]; const float* eb1 = (const float*)d_in[20];
    const float* ew2 = (const float*)d_in[21]; const float* eb2 = (const float*)d_in[22];
    const float* nw1 = (const float*)d_in[23]; const float* nb1 = (const float*)d_in[24];
    const float* nw2 = (const float*)d_in[25]; const float* nb2 = (const float*)d_in[26];
    float* out = (float*)d_out;

    float* ws    = (float*)d_ws;
    float* h_new = ws;                                   // N*D
    float* agg   = h_new + (size_t)N_NODES * D;          // N*D
    float* cnt   = agg + (size_t)N_NODES * D;            // N
    float* Kt    = cnt + N_NODES;                        // B*T*D
    float* Vt    = Kt + (size_t)BATCH * T * D;           // B*T*D
    float* lip   = Vt + (size_t)BATCH * T * D;           // B*9

    hipMemsetAsync(agg, 0, ((size_t)N_NODES * D + N_NODES) * sizeof(float), stream);
    prep_kernel<<<BATCH, 256, 0, stream>>>(cond, wk, bk, wv, bv, lat, Kt, Vt, lip);
    attn_kernel<<<(N_NODES + ATILE - 1) / ATILE, 256, 0, stream>>>(
        node_features, node2graph, frac, Kt, Vt, wq, bq, wo, bo, sw1, sb1, sw2, sb2, h_new);
    edge_kernel<<<N_EDGES / 64, 256, 0, stream>>>(
        h_new, frac, edges, e2g, lip, ew1, eb1, ew2, eb2, agg, cnt);
    node_kernel<<<(N_NODES + 63) / 64, 256, 0, stream>>>(
        node_features, h_new, agg, cnt, nw1, nb1, nw2, nb2, out);
}

// Round 4
// 854.165 us; speedup vs baseline: 4.0836x; 2.0463x over previous
//
#include <hip/hip_runtime.h>
#include <math.h>

#define N_NODES 50000
#define N_EDGES 800000
#define BATCH   256
#define D       128
#define T       8

#define LDS_S   132   // padded stride for 128-wide fp32 LDS tiles
#define LDA_E   68    // padded stride for 64-wide fp32 LDS chunks

// fp16 edge-MLP geometry
#define KPAD    288   // 268 -> 288 (9 x 32)
#define AS_S    296   // A-tile stride in halfs: 148 words, 148%32=20 -> 2-way max on b128 frag reads
#define A2_S    136   // intermediate stride: 68 words, 68%32=4 -> 2-way max

typedef _Float16 f16;
typedef f16  f16x4 __attribute__((ext_vector_type(4)));
typedef f16  f16x8 __attribute__((ext_vector_type(8)));
typedef float f32x4_t __attribute__((ext_vector_type(4)));

__device__ __forceinline__ float silu_f(float v) {
    return v / (1.0f + __expf(-v));
}

// ---------------- weight convert/transpose: ew1->W1t [128n][288k] f16, ew2->W2t [128n][128k] f16 ----
__global__ __launch_bounds__(256) void convert_kernel(
    const float* __restrict__ ew1, const float* __restrict__ ew2,
    f16* __restrict__ W1t, f16* __restrict__ W2t)
{
    int i = blockIdx.x * 256 + threadIdx.x;
    if (i < 128 * KPAD) {
        int n = i / KPAD, k = i % KPAD;
        W1t[i] = (k < 268) ? (f16)ew1[k * D + n] : (f16)0.f;
    } else if (i < 128 * KPAD + 128 * 128) {
        int j = i - 128 * KPAD;
        int n = j >> 7, k = j & 127;
        W2t[j] = (f16)ew2[k * D + n];
    }
}

// ---------------- prep: K/V projections of cond tokens + lattice grams ----------------
__global__ __launch_bounds__(256) void prep_kernel(
    const float* __restrict__ cond,   // [B,T,D]
    const float* __restrict__ wk, const float* __restrict__ bk,
    const float* __restrict__ wv, const float* __restrict__ bv,
    const float* __restrict__ lat,    // [B,3,3]
    float* __restrict__ Kout, float* __restrict__ Vout, float* __restrict__ lip)
{
    __shared__ float condS[T * D];
    int b = blockIdx.x, tid = threadIdx.x;
    {
        const float4* src = (const float4*)(cond + (size_t)b * T * D);
        ((float4*)condS)[tid] = src[tid];
    }
    __syncthreads();
    #pragma unroll
    for (int i = 0; i < 8; ++i) {
        int idx = tid + i * 256;
        int t = idx >> 7, d = idx & 127;
        float accK = bk[d], accV = bv[d];
        const float* c = condS + t * D;
        #pragma unroll 4
        for (int j = 0; j < D; ++j) {
            float cv = c[j];
            accK += cv * wk[j * D + d];
            accV += cv * wv[j * D + d];
        }
        Kout[(size_t)b * T * D + idx] = accK;
        Vout[(size_t)b * T * D + idx] = accV;
    }
    if (tid < 9) {
        int i = tid / 3, k = tid % 3;
        const float* Lb = lat + b * 9;
        float s = 0.f;
        #pragma unroll
        for (int j = 0; j < 3; ++j) s += Lb[i * 3 + j] * Lb[k * 3 + j];
        lip[b * 9 + tid] = s;
    }
}

// ---------------- fused cross-attention (tile of 32 nodes) ----------------
#define ATILE 32
__global__ __launch_bounds__(256) void attn_kernel(
    const float* __restrict__ h,          // node_features [N,D]
    const int*   __restrict__ node2graph,
    const float* __restrict__ frac,       // [N,3]
    const float* __restrict__ Kt, const float* __restrict__ Vt,  // [B,T,D]
    const float* __restrict__ wq, const float* __restrict__ bq,
    const float* __restrict__ wo, const float* __restrict__ bo,
    const float* __restrict__ sw1, const float* __restrict__ sb1,
    const float* __restrict__ sw2, const float* __restrict__ sb2,
    float* __restrict__ h_new)
{
    __shared__ float hs[ATILE * LDS_S];    // residual / GEMM-A
    __shared__ float buf[ATILE * LDS_S];   // tb -> Q -> ca
    __shared__ float encs[ATILE * 24];
    __shared__ float scS[ATILE * T];
    __shared__ float bS[ATILE * T];
    __shared__ int   gS[ATILE];

    int tid = threadIdx.x;
    int n0 = blockIdx.x * ATILE;
    int rows = min(ATILE, N_NODES - n0);

    // phase 0: stage h tile, graph ids, fourier enc
    #pragma unroll
    for (int i = 0; i < 4; ++i) {
        int q = tid + i * 256;
        int m = q >> 5, c4 = q & 31;
        float4 v = make_float4(0.f, 0.f, 0.f, 0.f);
        if (m < rows) v = *(const float4*)(h + (size_t)(n0 + m) * D + c4 * 4);
        *(float4*)(hs + m * LDS_S + c4 * 4) = v;
    }
    if (tid < ATILE) gS[tid] = node2graph[min(n0 + tid, N_NODES - 1)];
    for (int idx = tid; idx < ATILE * 24; idx += 256) {
        int m = idx / 24, j = idx % 24;
        float val = 0.f;
        if (m < rows) {
            int jj = (j < 12) ? j : j - 12;
            int a = jj >> 2, f = jj & 3;
            float ph = frac[(n0 + m) * 3 + a] * ((float)(1 << f) * 3.14159265358979323846f);
            val = (j < 12) ? sinf(ph) : cosf(ph);
        }
        encs[idx] = val;
    }
    __syncthreads();

    int rowg = tid >> 4, colg = tid & 15;
    int r0 = rowg * 2, c0 = colg * 8;      // TM=2, TN=8

    // phase 1: tb = silu(encs @ sw1 + sb1) -> buf
    {
        float acc[2][8];
        #pragma unroll
        for (int i = 0; i < 2; ++i)
            #pragma unroll
            for (int j = 0; j < 8; ++j) acc[i][j] = 0.f;
        #pragma unroll 4
        for (int k = 0; k < 24; ++k) {
            float a0 = encs[(r0 + 0) * 24 + k];
            float a1 = encs[(r0 + 1) * 24 + k];
            float4 w0 = *(const float4*)(sw1 + k * D + c0);
            float4 w1 = *(const float4*)(sw1 + k * D + c0 + 4);
            float w[8] = {w0.x, w0.y, w0.z, w0.w, w1.x, w1.y, w1.z, w1.w};
            #pragma unroll
            for (int j = 0; j < 8; ++j) { acc[0][j] += a0 * w[j]; acc[1][j] += a1 * w[j]; }
        }
        #pragma unroll
        for (int i = 0; i < 2; ++i)
            #pragma unroll
            for (int j = 0; j < 8; ++j) {
                float v = acc[i][j] + sb1[c0 + j];
                buf[(r0 + i) * LDS_S + c0 + j] = silu_f(v);
            }
    }
    __syncthreads();

    // bias = tb @ sw2 + sb2
    for (int idx = tid; idx < ATILE * T; idx += 256) {
        int m = idx >> 3, t = idx & 7;
        float s = sb2[t];
        #pragma unroll 4
        for (int j = 0; j < D; ++j) s += buf[m * LDS_S + j] * sw2[j * T + t];
        bS[idx] = s;
    }
    __syncthreads();

    // phase 2: Q = hs @ wq + bq -> buf
    {
        float acc[2][8];
        #pragma unroll
        for (int i = 0; i < 2; ++i)
            #pragma unroll
            for (int j = 0; j < 8; ++j) acc[i][j] = 0.f;
        #pragma unroll 4
        for (int k = 0; k < D; ++k) {
            float a0 = hs[(r0 + 0) * LDS_S + k];
            float a1 = hs[(r0 + 1) * LDS_S + k];
            float4 w0 = *(const float4*)(wq + k * D + c0);
            float4 w1 = *(const float4*)(wq + k * D + c0 + 4);
            float w[8] = {w0.x, w0.y, w0.z, w0.w, w1.x, w1.y, w1.z, w1.w};
            #pragma unroll
            for (int j = 0; j < 8; ++j) { acc[0][j] += a0 * w[j]; acc[1][j] += a1 * w[j]; }
        }
        __syncthreads();
        #pragma unroll
        for (int i = 0; i < 2; ++i)
            #pragma unroll
            for (int j = 0; j < 8; ++j)
                buf[(r0 + i) * LDS_S + c0 + j] = acc[i][j] + bq[c0 + j];
    }
    __syncthreads();

    // phase 3: scores + softmax
    for (int idx = tid; idx < ATILE * T; idx += 256) {
        int m = idx >> 3, t = idx & 7;
        const float* Kp = Kt + ((size_t)gS[m] * T + t) * D;
        float s = 0.f;
        #pragma unroll 4
        for (int j = 0; j < D; ++j) s += buf[m * LDS_S + j] * Kp[j];
        scS[idx] = s * 0.08838834764831845f + bS[idx];   // 1/sqrt(128)
    }
    __syncthreads();
    if (tid < ATILE) {
        float mx = -1e30f;
        #pragma unroll
        for (int t = 0; t < T; ++t) mx = fmaxf(mx, scS[tid * T + t]);
        float e[T], sum = 0.f;
        #pragma unroll
        for (int t = 0; t < T; ++t) { e[t] = __expf(scS[tid * T + t] - mx); sum += e[t]; }
        float inv = 1.f / sum;
        #pragma unroll
        for (int t = 0; t < T; ++t) scS[tid * T + t] = e[t] * inv;
    }
    __syncthreads();

    // phase 4: ca = attn @ V  -> buf (Q dead)
    #pragma unroll
    for (int i = 0; i < 16; ++i) {
        int idx = tid + i * 256;
        int m = idx >> 7, c = idx & 127;
        const float* Vp = Vt + (size_t)gS[m] * T * D + c;
        float s = 0.f;
        #pragma unroll
        for (int t = 0; t < T; ++t) s += scS[m * T + t] * Vp[t * D];
        buf[m * LDS_S + c] = s;
    }
    __syncthreads();

    // phase 5: h_new = hs + buf @ wo + bo
    {
        float acc[2][8];
        #pragma unroll
        for (int i = 0; i < 2; ++i)
            #pragma unroll
            for (int j = 0; j < 8; ++j) acc[i][j] = 0.f;
        #pragma unroll 4
        for (int k = 0; k < D; ++k) {
            float a0 = buf[(r0 + 0) * LDS_S + k];
            float a1 = buf[(r0 + 1) * LDS_S + k];
            float4 w0 = *(const float4*)(wo + k * D + c0);
            float4 w1 = *(const float4*)(wo + k * D + c0 + 4);
            float w[8] = {w0.x, w0.y, w0.z, w0.w, w1.x, w1.y, w1.z, w1.w};
            #pragma unroll
            for (int j = 0; j < 8; ++j) { acc[0][j] += a0 * w[j]; acc[1][j] += a1 * w[j]; }
        }
        #pragma unroll
        for (int i = 0; i < 2; ++i) {
            int m = r0 + i;
            if (m < rows) {
                #pragma unroll
                for (int j = 0; j < 8; ++j) {
                    float v = acc[i][j] + bo[c0 + j] + hs[m * LDS_S + c0 + j];
                    h_new[(size_t)(n0 + m) * D + c0 + j] = v;
                }
            }
        }
    }
}

// ---------------- MFMA fp16 edge MLP + register-direct atomic scatter (tile of 64 edges) -----
// 4 waves x 256 thr; wave w owns output cols [w*32, w*32+32).
// A-tile [64 rows][288 k] f16 in LDS (stride 296); W from pre-transposed f16 ws arrays.
// mfma_f32_16x16x32_f16: A-frag lane l = row (l&15), k = (l>>4)*8+e (k-contig 8/lane);
// B-frag lane l = col (l&15), same k; C/D: col = l&15, row = (l>>4)*4 + reg (HW-verified).
__global__ __launch_bounds__(256) void edge_kernel(
    const float* __restrict__ h_new,
    const float* __restrict__ frac,
    const int*   __restrict__ edges,   // [2,E]
    const int*   __restrict__ e2g,
    const float* __restrict__ lip,     // [B,9]
    const f16*   __restrict__ W1t,     // [128][288]
    const f16*   __restrict__ W2t,     // [128][128]
    const float* __restrict__ eb1, const float* __restrict__ eb2,
    float* __restrict__ agg, float* __restrict__ cnt)
{
    __shared__ __align__(16) f16 As[64 * AS_S];   // 37,888 B; aliased by A2 [64*A2_S]
    __shared__ int e0S[64], e1S[64];

    int tid = threadIdx.x;
    int m0 = blockIdx.x * 64;
    if (tid < 64) {
        e0S[tid] = edges[m0 + tid];
        e1S[tid] = edges[N_EDGES + m0 + tid];
    }
    __syncthreads();

    // stage gathered h rows (fp32 -> fp16) into cols [0,128) (e0) and [128,256) (e1)
    #pragma unroll
    for (int half = 0; half < 2; ++half) {
        const int* srci = half ? e1S : e0S;
        #pragma unroll
        for (int it = 0; it < 8; ++it) {
            int idx = tid + it * 256;           // 0..2047
            int row = idx >> 5, c4 = idx & 31;  // 64 rows x 32 float4
            float4 v = *(const float4*)(h_new + (size_t)srci[row] * D + c4 * 4);
            f16x4 hv;
            hv.x = (f16)v.x; hv.y = (f16)v.y; hv.z = (f16)v.z; hv.w = (f16)v.w;
            *(f16x4*)(As + row * AS_S + half * 128 + c4 * 4) = hv;
        }
    }
    // tail: cols 256..264 lip(9), 265..267 fd(3)
    for (int idx = tid; idx < 64 * 12; idx += 256) {
        int row = idx / 12, j = idx % 12;
        float v;
        if (j < 9) v = lip[e2g[m0 + row] * 9 + j];
        else {
            int a = j - 9;
            float d = frac[e1S[row] * 3 + a] - frac[e0S[row] * 3 + a];
            v = d - floorf(d);
        }
        As[row * AS_S + 256 + j] = (f16)v;
    }
    // zero-pad cols 268..287
    for (int idx = tid; idx < 64 * 20; idx += 256) {
        int row = idx / 20, c = 268 + idx % 20;
        As[row * AS_S + c] = (f16)0.f;
    }
    __syncthreads();

    int wid  = tid >> 6;        // wave 0..3
    int lane = tid & 63;
    int lrow = lane & 15;       // A row within 16-block / output col within 16-block
    int kgrp = lane >> 4;       // k-subgroup 0..3

    // ---- GEMM1: [64 x 288] @ [288 x 128] -> acc[4 mb][2 nb] ----
    f32x4_t acc[4][2];
    #pragma unroll
    for (int mb = 0; mb < 4; ++mb)
        #pragma unroll
        for (int nb = 0; nb < 2; ++nb)
            acc[mb][nb] = (f32x4_t){0.f, 0.f, 0.f, 0.f};

    #pragma unroll
    for (int kk = 0; kk < KPAD / 32; ++kk) {
        int k0 = kk * 32 + kgrp * 8;
        f16x8 af[4];
        #pragma unroll
        for (int mb = 0; mb < 4; ++mb)
            af[mb] = *(const f16x8*)(As + (mb * 16 + lrow) * AS_S + k0);
        f16x8 bf[2];
        #pragma unroll
        for (int nb = 0; nb < 2; ++nb)
            bf[nb] = *(const f16x8*)(W1t + (size_t)(wid * 32 + nb * 16 + lrow) * KPAD + k0);
        #pragma unroll
        for (int mb = 0; mb < 4; ++mb)
            #pragma unroll
            for (int nb = 0; nb < 2; ++nb)
                acc[mb][nb] = __builtin_amdgcn_mfma_f32_16x16x32_f16(af[mb], bf[nb], acc[mb][nb], 0, 0, 0);
    }
    __syncthreads();   // all waves done reading As before aliased A2 write

    // silu + bias -> A2 (f16, stride 136), aliased over As
    f16* A2 = As;
    #pragma unroll
    for (int mb = 0; mb < 4; ++mb)
        #pragma unroll
        for (int nb = 0; nb < 2; ++nb) {
            int col = wid * 32 + nb * 16 + lrow;
            float bias = eb1[col];
            #pragma unroll
            for (int r = 0; r < 4; ++r) {
                int row = mb * 16 + kgrp * 4 + r;
                A2[row * A2_S + col] = (f16)silu_f(acc[mb][nb][r] + bias);
            }
        }
    __syncthreads();

    // ---- GEMM2: [64 x 128] @ [128 x 128] ----
    f32x4_t acc2[4][2];
    #pragma unroll
    for (int mb = 0; mb < 4; ++mb)
        #pragma unroll
        for (int nb = 0; nb < 2; ++nb)
            acc2[mb][nb] = (f32x4_t){0.f, 0.f, 0.f, 0.f};

    #pragma unroll
    for (int kk = 0; kk < 4; ++kk) {
        int k0 = kk * 32 + kgrp * 8;
        f16x8 af[4];
        #pragma unroll
        for (int mb = 0; mb < 4; ++mb)
            af[mb] = *(const f16x8*)(A2 + (mb * 16 + lrow) * A2_S + k0);
        f16x8 bf[2];
        #pragma unroll
        for (int nb = 0; nb < 2; ++nb)
            bf[nb] = *(const f16x8*)(W2t + (size_t)(wid * 32 + nb * 16 + lrow) * 128 + k0);
        #pragma unroll
        for (int mb = 0; mb < 4; ++mb)
            #pragma unroll
            for (int nb = 0; nb < 2; ++nb)
                acc2[mb][nb] = __builtin_amdgcn_mfma_f32_16x16x32_f16(af[mb], bf[nb], acc2[mb][nb], 0, 0, 0);
    }

    // epilogue: silu + atomic scatter (16-lane groups cover aligned 64B runs)
    #pragma unroll
    for (int mb = 0; mb < 4; ++mb)
        #pragma unroll
        for (int nb = 0; nb < 2; ++nb) {
            int col = wid * 32 + nb * 16 + lrow;
            float bias = eb2[col];
            #pragma unroll
            for (int r = 0; r < 4; ++r) {
                int row = mb * 16 + kgrp * 4 + r;
                float v = silu_f(acc2[mb][nb][r] + bias);
                atomicAdd(&agg[(size_t)e0S[row] * D + col], v);
            }
        }
    if (tid < 64) atomicAdd(&cnt[e0S[tid]], 1.0f);
}

// ---------------- fused node MLP + residual (tile of 64 nodes) ----------------
__global__ __launch_bounds__(256) void node_kernel(
    const float* __restrict__ node_features,
    const float* __restrict__ h_new,
    const float* __restrict__ agg, const float* __restrict__ cnt,
    const float* __restrict__ nw1, const float* __restrict__ nb1,
    const float* __restrict__ nw2, const float* __restrict__ nb2,
    float* __restrict__ out)
{
    __shared__ float t1[64 * LDS_S];   // stride 132: 4-row-group broadcast reads land 2-way, not 4-way
    float* As = t1;                    // aliased (LDA_E=68 stride, smaller footprint)
    int tid = threadIdx.x;
    int n0 = blockIdx.x * 64;
    int rows = min(64, N_NODES - n0);
    int rowg = tid >> 4, colg = tid & 15;
    int r0 = rowg * 4, c0 = colg * 8;
    float acc[4][8];
    #pragma unroll
    for (int i = 0; i < 4; ++i)
        #pragma unroll
        for (int j = 0; j < 8; ++j) acc[i][j] = 0.f;

    for (int ch = 0; ch < 4; ++ch) {
        __syncthreads();
        #pragma unroll
        for (int i = 0; i < 4; ++i) {
            int q = tid + i * 256;
            int m = q >> 4, c4 = q & 15;
            float4 v = make_float4(0.f, 0.f, 0.f, 0.f);
            if (m < rows) {
                int col = (ch & 1) * 64 + c4 * 4;
                if (ch < 2) {
                    v = *(const float4*)(h_new + (size_t)(n0 + m) * D + col);
                } else {
                    float4 a = *(const float4*)(agg + (size_t)(n0 + m) * D + col);
                    float inv = 1.0f / fmaxf(cnt[n0 + m], 1.0f);
                    v = make_float4(a.x * inv, a.y * inv, a.z * inv, a.w * inv);
                }
            }
            *(float4*)(As + m * LDA_E + c4 * 4) = v;
        }
        __syncthreads();
        int kb = ch * 64;
        #pragma unroll 4
        for (int k = 0; k < 64; ++k) {
            float a0 = As[(r0 + 0) * LDA_E + k];
            float a1 = As[(r0 + 1) * LDA_E + k];
            float a2 = As[(r0 + 2) * LDA_E + k];
            float a3 = As[(r0 + 3) * LDA_E + k];
            float4 w0 = *(const float4*)(nw1 + (kb + k) * D + c0);
            float4 w1 = *(const float4*)(nw1 + (kb + k) * D + c0 + 4);
            float w[8] = {w0.x, w0.y, w0.z, w0.w, w1.x, w1.y, w1.z, w1.w};
            #pragma unroll
            for (int j = 0; j < 8; ++j) {
                acc[0][j] += a0 * w[j]; acc[1][j] += a1 * w[j];
                acc[2][j] += a2 * w[j]; acc[3][j] += a3 * w[j];
            }
        }
    }
    __syncthreads();   // done reading As before aliased t1 write
    #pragma unroll
    for (int i = 0; i < 4; ++i)
        #pragma unroll
        for (int j = 0; j < 8; ++j)
            t1[(r0 + i) * LDS_S + c0 + j] = silu_f(acc[i][j] + nb1[c0 + j]);
    __syncthreads();

    float acc2[4][8];
    #pragma unroll
    for (int i = 0; i < 4; ++i)
        #pragma unroll
        for (int j = 0; j < 8; ++j) acc2[i][j] = 0.f;
    #pragma unroll 4
    for (int k = 0; k < D; ++k) {
        float a0 = t1[(r0 + 0) * LDS_S + k];
        float a1 = t1[(r0 + 1) * LDS_S + k];
        float a2 = t1[(r0 + 2) * LDS_S + k];
        float a3 = t1[(r0 + 3) * LDS_S + k];
        float4 w0 = *(const float4*)(nw2 + k * D + c0);
        float4 w1 = *(const float4*)(nw2 + k * D + c0 + 4);
        float w[8] = {w0.x, w0.y, w0.z, w0.w, w1.x, w1.y, w1.z, w1.w};
        #pragma unroll
        for (int j = 0; j < 8; ++j) {
            acc2[0][j] += a0 * w[j]; acc2[1][j] += a1 * w[j];
            acc2[2][j] += a2 * w[j]; acc2[3][j] += a3 * w[j];
        }
    }
    #pragma unroll
    for (int i = 0; i < 4; ++i) {
        int m = r0 + i;
        if (m < rows) {
            #pragma unroll
            for (int j = 0; j < 8; ++j) {
                float v = silu_f(acc2[i][j] + nb2[c0 + j]);
                out[(size_t)(n0 + m) * D + c0 + j] =
                    node_features[(size_t)(n0 + m) * D + c0 + j] + v;
            }
        }
    }
}

extern "C" void kernel_launch(void* const* d_in, const int* in_sizes, int n_in,
                              void* d_out, int out_size, void* d_ws, size_t ws_size,
                              hipStream_t stream) {
    const float* node_features = (const float*)d_in[0];
    const float* cond          = (const float*)d_in[1];
    const int*   node2graph    = (const int*)d_in[2];
    const float* frac          = (const float*)d_in[3];
    const float* lat           = (const float*)d_in[4];
    const int*   edges         = (const int*)d_in[5];
    const int*   e2g           = (const int*)d_in[6];
    const float* wq = (const float*)d_in[7];  const float* bq = (const float*)d_in[8];
    const float* wk = (const float*)d_in[9];  const float* bk = (const float*)d_in[10];
    const float* wv = (const float*)d_in[11]; const float* bv = (const float*)d_in[12];
    const float* wo = (const float*)d_in[13]; const float* bo = (const float*)d_in[14];
    const float* sw1 = (const float*)d_in[15]; const float* sb1 = (const float*)d_in[16];
    const float* sw2 = (const float*)d_in[17]; const float* sb2 = (const float*)d_in[18];
    const float* ew1 = (const float*)d_in[19]; const float* eb1 = (const float*)d_in[20];
    const float* ew2 = (const float*)d_in[21]; const float* eb2 = (const float*)d_in[22];
    const float* nw1 = (const float*)d_in[23]; const float* nb1 = (const float*)d_in[24];
    const float* nw2 = (const float*)d_in[25]; const float* nb2 = (const float*)d_in[26];
    float* out = (float*)d_out;

    float* ws    = (float*)d_ws;
    float* h_new = ws;                                   // N*D f32
    float* agg   = h_new + (size_t)N_NODES * D;          // N*D f32
    float* cnt   = agg + (size_t)N_NODES * D;            // N f32
    float* Kt    = cnt + N_NODES;                        // B*T*D f32
    float* Vt    = Kt + (size_t)BATCH * T * D;           // B*T*D f32
    float* lip   = Vt + (size_t)BATCH * T * D;           // B*9 f32
    f16*   W1t   = (f16*)(lip + BATCH * 9 + 3);          // 128*288 f16 (16B-aligned: offset even)
    f16*   W2t   = W1t + 128 * KPAD;                     // 128*128 f16

    hipMemsetAsync(agg, 0, ((size_t)N_NODES * D + N_NODES) * sizeof(float), stream);
    convert_kernel<<<(128 * KPAD + 128 * 128 + 255) / 256, 256, 0, stream>>>(ew1, ew2, W1t, W2t);
    prep_kernel<<<BATCH, 256, 0, stream>>>(cond, wk, bk, wv, bv, lat, Kt, Vt, lip);
    attn_kernel<<<(N_NODES + ATILE - 1) / ATILE, 256, 0, stream>>>(
        node_features, node2graph, frac, Kt, Vt, wq, bq, wo, bo, sw1, sb1, sw2, sb2, h_new);
    edge_kernel<<<N_EDGES / 64, 256, 0, stream>>>(
        h_new, frac, edges, e2g, lip, W1t, W2t, eb1, eb2, agg, cnt);
    node_kernel<<<(N_NODES + 63) / 64, 256, 0, stream>>>(
        node_features, h_new, agg, cnt, nw1, nb1, nw2, nb2, out);
}